// Round 10
// baseline (226.128 us; speedup 1.0000x reference)
//
#include <hip/hip_runtime.h>
#include <math.h>

#define TOK 4096
#define DM  512
#define HF  2048
#define NE  8

typedef __bf16 bf16x8 __attribute__((ext_vector_type(8)));
typedef float  floatx16 __attribute__((ext_vector_type(16)));

// float -> bf16 (round-to-nearest-even), raw ushort bits
__device__ __forceinline__ unsigned short f2b(float f) {
    union { float f; unsigned u; } v; v.f = f;
    return (unsigned short)((v.u + 0x7fffu + ((v.u >> 16) & 1u)) >> 16);
}

// async global->LDS, 16 bytes per lane (dest = wave-uniform base + lane*16)
__device__ __forceinline__ void load_lds16(const void* g, void* l) {
    __builtin_amdgcn_global_load_lds(
        (__attribute__((address_space(1))) unsigned int*)g,
        (__attribute__((address_space(3))) unsigned int*)l, 16, 0, 0);
}

// one wave per token: logits = x[t] @ Wr + br ; routes[t] = argmax. NO atomics.
__global__ __launch_bounds__(256)
void k_router(const float* __restrict__ x, const float* __restrict__ Wr,
              const float* __restrict__ br, int* __restrict__ routes) {
    int t = blockIdx.x * 4 + (threadIdx.x >> 6);
    int lane = threadIdx.x & 63;
    float acc[NE];
#pragma unroll
    for (int e = 0; e < NE; e++) acc[e] = 0.f;
    const float* xr = x + (size_t)t * DM;
#pragma unroll
    for (int d0 = 0; d0 < DM; d0 += 64) {
        float xv = xr[d0 + lane];
        const float* w = Wr + (size_t)(d0 + lane) * NE;
#pragma unroll
        for (int e = 0; e < NE; e++) acc[e] += xv * w[e];
    }
#pragma unroll
    for (int off = 32; off > 0; off >>= 1) {
#pragma unroll
        for (int e = 0; e < NE; e++) acc[e] += __shfl_down(acc[e], off, 64);
    }
    if (lane == 0) {
        int best = 0; float bv = acc[0] + br[0];
#pragma unroll
        for (int e = 1; e < NE; e++) {
            float v = acc[e] + br[e];
            if (v > bv) { bv = v; best = e; }   // strict > == first-max (jnp.argmax)
        }
        routes[t] = best;
    }
}

// Single block: histogram + prefix + perm placement, all contention in LDS.
__global__ __launch_bounds__(1024)
void k_organize(const int* __restrict__ routes, int* __restrict__ offsets,
                int* __restrict__ perm) {
    __shared__ int cnt[NE], cur[NE], off[NE + 1];
    int tid = threadIdx.x;
    if (tid < NE) { cnt[tid] = 0; cur[tid] = 0; }
    __syncthreads();
    int t0 = tid * 4;
    int4 r = *(const int4*)&routes[t0];
    atomicAdd(&cnt[r.x], 1); atomicAdd(&cnt[r.y], 1);
    atomicAdd(&cnt[r.z], 1); atomicAdd(&cnt[r.w], 1);
    __syncthreads();
    if (tid == 0) {
        int s = 0;
#pragma unroll
        for (int e = 0; e < NE; e++) { off[e] = s; s += cnt[e]; }
        off[NE] = s;
    }
    __syncthreads();
    int p;
    p = atomicAdd(&cur[r.x], 1); perm[off[r.x] + p] = t0;
    p = atomicAdd(&cur[r.y], 1); perm[off[r.y] + p] = t0 + 1;
    p = atomicAdd(&cur[r.z], 1); perm[off[r.z] + p] = t0 + 2;
    p = atomicAdd(&cur[r.w], 1); perm[off[r.w] + p] = t0 + 3;
    if (tid < NE + 1) offsets[tid] = off[tid];
}

// gather x rows into expert-grouped bf16 matrix xg[g][d]; 4 rows per block
__global__ __launch_bounds__(256)
void k_gather(const float* __restrict__ x, const int* __restrict__ perm,
              unsigned short* __restrict__ xg) {
    int g = blockIdx.x * 4 + (threadIdx.x >> 6);
    int lane = threadIdx.x & 63;
    int t = perm[g];
    const float4* src = (const float4*)(x + (size_t)t * DM);
    unsigned short* dst = xg + (size_t)g * DM;
#pragma unroll
    for (int i = 0; i < 2; i++) {
        int idx = lane + i * 64;
        float4 v = src[idx];
        ushort4 o; o.x = f2b(v.x); o.y = f2b(v.y); o.z = f2b(v.z); o.w = f2b(v.w);
        *(ushort4*)(dst + idx * 4) = o;
    }
}

// Both weight transposes in ONE dispatch. blockIdx.x < 256: W1 tile; else W2.
// [E][K][N] fp32 -> [E][N][K] bf16, 64x64 tiles.
__global__ __launch_bounds__(256)
void k_transpose(const float* __restrict__ W1, unsigned short* __restrict__ W1t,
                 const float* __restrict__ W2, unsigned short* __restrict__ W2t) {
    int e = blockIdx.z;
    int bt = blockIdx.x;
    const float* src; unsigned short* dst; int K, N, n0, k0;
    if (bt < 256) {            // W1: K=DM(512)=8 k-tiles, N=HF(2048)=32 n-tiles
        K = DM; N = HF;
        n0 = (bt & 31) * 64; k0 = (bt >> 5) * 64;
        src = W1 + (size_t)e * K * N; dst = W1t + (size_t)e * N * K;
    } else {                   // W2: K=HF(2048)=32 k-tiles, N=DM(512)=8 n-tiles
        bt -= 256; K = HF; N = DM;
        n0 = (bt & 7) * 64; k0 = (bt >> 3) * 64;
        src = W2 + (size_t)e * K * N; dst = W2t + (size_t)e * N * K;
    }
    __shared__ unsigned short tile[64][68];
    int tid = threadIdx.x;
    int tr = tid >> 4;   // 0..15
    int tc = tid & 15;   // 0..15
#pragma unroll
    for (int rr = 0; rr < 4; rr++) {
        int r = tr * 4 + rr;
        const float4 v = *(const float4*)(src + (size_t)(k0 + r) * N + n0 + tc * 4);
        tile[r][tc * 4 + 0] = f2b(v.x);
        tile[r][tc * 4 + 1] = f2b(v.y);
        tile[r][tc * 4 + 2] = f2b(v.z);
        tile[r][tc * 4 + 3] = f2b(v.w);
    }
    __syncthreads();
#pragma unroll
    for (int rr = 0; rr < 4; rr++) {
        int nrow = tr * 4 + rr;
        ushort4 o;
        o.x = tile[tc * 4 + 0][nrow];
        o.y = tile[tc * 4 + 1][nrow];
        o.z = tile[tc * 4 + 2][nrow];
        o.w = tile[tc * 4 + 3][nrow];
        *(ushort4*)(dst + (size_t)(n0 + nrow) * K + k0 + tc * 4) = o;
    }
}

// ---------------------------------------------------------------------------
// Round-10 GEMM: barrier-LIGHT K-loop (r8 de-risked).
//  * A staged to LDS in TWO 32 KB phases (64 rows x 256 K each) -> 3 barriers
//    per block total (vs 16 in r7), 8 DMAs/thread per stage (vs 16 in r8),
//    32 KB LDS (vs r8's 64 KB static-limit edge).
//  * B streamed to REGISTERS via plain global loads -> compiler emits
//    fine-grained s_waitcnt vmcnt(N), software-pipelined across chunks.
//  * Block = 64 x 256 tile, 4 waves side-by-side in N (each 64x64, 2x2
//    32x32x16 frags). 2 blocks/CU, 8 independent waves/CU.
//  * FULL 5-bit LDS swizzle: phys_chunk = local_chunk ^ (row & 31) over the
//    32 16B-chunks per row-phase -> fragment reads hit 32 distinct bank-quads
//    (r7/r8's 3-bit swizzle left 4-way conflicts: 1.18M conflict cycles).
// FC1 (KSPLIT=1): C = GELU(acc+b1) -> hg bf16.  FC2 (KSPLIT=4): -> pbuf.
// ---------------------------------------------------------------------------
template <int KSTRIDE, int ND, bool FC1, int KSPLIT>
__global__ __launch_bounds__(256, 2)
void k_gemm(const unsigned short* __restrict__ A,
            const unsigned short* __restrict__ Bt,
            const float* __restrict__ bias,
            unsigned short* __restrict__ hg,
            float* __restrict__ pbuf,
            const int* __restrict__ offsets) {
    const int e  = blockIdx.z / KSPLIT;
    const int ks = blockIdx.z % KSPLIT;
    const int seg0 = offsets[e];
    const int cnt  = offsets[e + 1] - seg0;
    const int m0 = blockIdx.y * 64;
    if (m0 >= cnt) return;
    const int n0 = blockIdx.x * 256;
    const int kbase = ks * 512;                 // ushort offset into each row

    __shared__ unsigned short As[64 * 256];     // 32 KB (one 256-K phase)

    const unsigned short* Aexp = A + (size_t)seg0 * KSTRIDE;
    const unsigned short* Brow = Bt + (size_t)e * ND * KSTRIDE;

    const int tid  = threadIdx.x;
    const int lane = tid & 63;
    const int wave = tid >> 6;
    const int wn = wave * 64;

    // stage phase p (k-range [p*256, p*256+256)): 8 DMAs/thread.
    // LDS linear: row r = off/512B, slot s = (off%512)/16B. For off=i*4096+tid*16:
    // r = i*8 + (tid>>5), s = tid&31. Source chunk = s ^ (r&31)  (5-bit swizzle).
    auto stage = [&](int p) {
        const int fo = tid * 16;
        const int rr = tid >> 5;
        const int s  = tid & 31;
#pragma unroll
        for (int i = 0; i < 8; i++) {
            int r = i * 8 + rr;
            int c = s ^ (r & 31);
            load_lds16(Aexp + (size_t)(m0 + r) * KSTRIDE + kbase + p * 256 + c * 8,
                       (char*)As + i * 4096 + fo);
        }
    };

    const int fr = lane & 31;
    const int hi = lane >> 5;

    floatx16 acc[2][2];
#pragma unroll
    for (int i = 0; i < 2; i++)
#pragma unroll
        for (int j = 0; j < 2; j++)
#pragma unroll
            for (int r = 0; r < 16; r++) acc[i][j][r] = 0.f;

    stage(0);
    __syncthreads();   // phase-0 A resident

    // ---- K loop: 8 chunks (64 ushorts each) x 4 k-steps; B in registers ----
    const unsigned short* bp0 = Brow + (size_t)(n0 + wn + fr) * KSTRIDE + kbase + hi * 8;
    const unsigned short* bp1 = bp0 + (size_t)32 * KSTRIDE;

    bf16x8 bc[2][4], bn[2][4];
#pragma unroll
    for (int t = 0; t < 4; t++) {
        bc[0][t] = *(const bf16x8*)(bp0 + t * 16);
        bc[1][t] = *(const bf16x8*)(bp1 + t * 16);
    }
#pragma unroll
    for (int c = 0; c < 8; c++) {
        if (c == 4) {          // phase boundary: swap A tile
            __syncthreads();   // all waves done reading phase 0
            stage(1);
            __syncthreads();   // phase-1 A resident
        }
        if (c < 7) {
#pragma unroll
            for (int t = 0; t < 4; t++) {
                bn[0][t] = *(const bf16x8*)(bp0 + (c + 1) * 64 + t * 16);
                bn[1][t] = *(const bf16x8*)(bp1 + (c + 1) * 64 + t * 16);
            }
        }
        const int base = (c & 3) * 8;            // local 16B-chunk base in phase
#pragma unroll
        for (int t = 0; t < 4; t++) {
            const int local = base + t * 2 + hi; // local 16B chunk 0..31
            bf16x8 af[2];
#pragma unroll
            for (int i = 0; i < 2; i++) {
                int r = i * 32 + fr;
                int phys = local ^ (r & 31);
                af[i] = *(const bf16x8*)&As[r * 256 + phys * 8];
            }
#pragma unroll
            for (int i = 0; i < 2; i++)
#pragma unroll
                for (int j = 0; j < 2; j++)
                    acc[i][j] = __builtin_amdgcn_mfma_f32_32x32x16_bf16(af[i], bc[j][t], acc[i][j], 0, 0, 0);
        }
#pragma unroll
        for (int j = 0; j < 2; j++)
#pragma unroll
            for (int t = 0; t < 4; t++) bc[j][t] = bn[j][t];
    }

    // epilogue: 32x32 C/D layout col=lane&31, row=(reg&3)+8*(reg>>2)+4*(lane>>5)
    const int rbase = 4 * hi;
#pragma unroll
    for (int i = 0; i < 2; i++) {
#pragma unroll
        for (int j = 0; j < 2; j++) {
            int col = n0 + wn + j * 32 + fr;
            float bv = FC1 ? bias[(size_t)e * ND + col] : 0.f;
#pragma unroll
            for (int r = 0; r < 16; r++) {
                int grow = m0 + i * 32 + rbase + (r & 3) + 8 * (r >> 2);
                if (grow < cnt) {
                    float v = acc[i][j][r] + bv;
                    if constexpr (FC1) {
                        v = 0.5f * v * (1.0f + erff(v * 0.70710678118654752f)); // exact GELU
                        hg[(size_t)(seg0 + grow) * ND + col] = f2b(v);
                    } else {
                        pbuf[((size_t)ks * TOK + seg0 + grow) * ND + col] = v;
                    }
                }
            }
        }
    }
}

// out[perm[g]][:] = sum_ks pbuf[ks][g][:] + b2[e(g)][:]
__global__ __launch_bounds__(128)
void k_reduce(const float* __restrict__ pbuf, const int* __restrict__ perm,
              const int* __restrict__ offsets, const float* __restrict__ b2,
              float* __restrict__ out) {
    int g = blockIdx.x;
    int tok = perm[g];
    int e = 0;
#pragma unroll
    for (int i = 1; i < NE; i++) e += (g >= offsets[i]);
    int c = threadIdx.x * 4;
    float4 o = *(const float4*)&b2[(size_t)e * DM + c];
#pragma unroll
    for (int ks = 0; ks < 4; ks++) {
        float4 a = *(const float4*)&pbuf[((size_t)ks * TOK + g) * DM + c];
        o.x += a.x; o.y += a.y; o.z += a.z; o.w += a.w;
    }
    *(float4*)&out[(size_t)tok * DM + c] = o;
}

extern "C" void kernel_launch(void* const* d_in, const int* in_sizes, int n_in,
                              void* d_out, int out_size, void* d_ws, size_t ws_size,
                              hipStream_t stream) {
    const float* x  = (const float*)d_in[0];
    const float* Wr = (const float*)d_in[1];
    const float* br = (const float*)d_in[2];
    const float* W1 = (const float*)d_in[3];
    const float* b1 = (const float*)d_in[4];
    const float* W2 = (const float*)d_in[5];
    const float* b2 = (const float*)d_in[6];
    float* out = (float*)d_out;

    char* ws = (char*)d_ws;
    int* routes  = (int*)ws;            // [4096]
    int* perm    = routes + TOK;        // [4096]
    int* offsets = perm + TOK;          // [9]
    unsigned short* xg  = (unsigned short*)(ws + 65536);     // [4096][512]  bf16  (4 MB)
    unsigned short* hg  = xg + (size_t)TOK * DM;             // [4096][2048] bf16  (16 MB)
    unsigned short* W1t = hg + (size_t)TOK * HF;             // [E][H][D]    bf16  (16.8 MB)
    unsigned short* W2t = W1t + (size_t)NE * HF * DM;        // [E][D][H]    bf16  (16.8 MB)
    float* pbuf = (float*)(W2t + (size_t)NE * DM * HF);      // [4][4096][512] fp32 (32 MB)
    // GEMM A-tile overruns past xg/hg ends land in the next buffer (valid
    // memory, non-NaN bf16 bit patterns); rows >= cnt never stored.

    k_router<<<TOK / 4, 256, 0, stream>>>(x, Wr, br, routes);
    k_organize<<<1, 1024, 0, stream>>>(routes, offsets, perm);
    k_gather<<<TOK / 4, 256, 0, stream>>>(x, perm, xg);
    k_transpose<<<dim3(512, 1, NE), 256, 0, stream>>>(W1, W1t, W2, W2t);
    // fc1: 64x256 tiles, 2-phase A staging, register-streamed B.
    k_gemm<512, HF, true, 1><<<dim3(HF / 256, TOK / 64, NE), 256, 0, stream>>>(
        xg, W1t, b1, hg, nullptr, offsets);
    // fc2: same structure, K split 4x512 -> pbuf; no atomics.
    k_gemm<2048, DM, false, 4><<<dim3(DM / 256, TOK / 64, NE * 4), 256, 0, stream>>>(
        hg, W2t, nullptr, nullptr, pbuf, offsets);
    k_reduce<<<TOK, 128, 0, stream>>>(pbuf, perm, offsets, b2, out);
}